// Round 1
// baseline (2595.577 us; speedup 1.0000x reference)
//
#include <hip/hip_runtime.h>

#define BATCHN 32
#define SEQN   2048
#define INSZ   128
#define HN     128
#define G4     512   // 4*H

#define OUT_MAIN ((size_t)BATCHN * SEQN * 2 * HN)   // 16,777,216 floats

__device__ __forceinline__ float sigf(float x) {
  return 1.0f / (1.0f + __expf(-x));
}
__device__ __forceinline__ float tanhfast(float x) {
  return 2.0f / (1.0f + __expf(-2.0f * x)) - 1.0f;
}

// ---------------------------------------------------------------------------
// Precompute XW[b][t][j] = x[b][t][:] @ Wi[:][j] + B[j]
// grid: 32 b * 32 t-tiles (64 t each) = 1024 blocks, 512 threads.
// Thread j owns gate column j; Wi column held in 128 VGPRs.
// ---------------------------------------------------------------------------
__global__ __launch_bounds__(512, 2) void precompute_xw(
    const float* __restrict__ x, const float* __restrict__ Wi,
    const float* __restrict__ B, float* __restrict__ XW) {
  const int j  = threadIdx.x;        // 0..511 gate column
  const int b  = blockIdx.x >> 5;    // 0..31
  const int tt = blockIdx.x & 31;    // t-tile

  __shared__ __align__(16) float xs[64][INSZ];   // 32 KiB

  const float* xsrc = x + ((size_t)b * SEQN + (size_t)tt * 64) * INSZ;
  for (int i = j; i < 64 * INSZ / 4; i += 512) {
    ((float4*)&xs[0][0])[i] = ((const float4*)xsrc)[i];
  }

  float wi[INSZ];
#pragma unroll
  for (int k = 0; k < INSZ; k++) wi[k] = Wi[(size_t)k * G4 + j];
  const float bj = B[j];
  __syncthreads();

  float* dst = XW + ((size_t)b * SEQN + (size_t)tt * 64) * G4 + j;
  for (int t = 0; t < 64; t++) {
    float a0 = bj, a1 = 0.f, a2 = 0.f, a3 = 0.f;
#pragma unroll
    for (int kk = 0; kk < INSZ / 16; kk++) {
      float4 x0 = *(const float4*)&xs[t][kk * 16 + 0];
      float4 x1 = *(const float4*)&xs[t][kk * 16 + 4];
      float4 x2 = *(const float4*)&xs[t][kk * 16 + 8];
      float4 x3 = *(const float4*)&xs[t][kk * 16 + 12];
      a0 += x0.x * wi[kk*16+ 0] + x0.y * wi[kk*16+ 1] + x0.z * wi[kk*16+ 2] + x0.w * wi[kk*16+ 3];
      a1 += x1.x * wi[kk*16+ 4] + x1.y * wi[kk*16+ 5] + x1.z * wi[kk*16+ 6] + x1.w * wi[kk*16+ 7];
      a2 += x2.x * wi[kk*16+ 8] + x2.y * wi[kk*16+ 9] + x2.z * wi[kk*16+10] + x2.w * wi[kk*16+11];
      a3 += x3.x * wi[kk*16+12] + x3.y * wi[kk*16+13] + x3.z * wi[kk*16+14] + x3.w * wi[kk*16+15];
    }
    dst[(size_t)t * G4] = (a0 + a1) + (a2 + a3);
  }
}

// ---------------------------------------------------------------------------
// Recurrence: 64 blocks = (batch 32) x (dir 2), one chain per block/CU.
// 512 threads; thread j owns gate column j with Wh column in 128 VGPRs.
// h lives in LDS (broadcast reads); gates exchanged via LDS; c in register
// of threads j<128. 2 barriers per step.
// ---------------------------------------------------------------------------
__global__ __launch_bounds__(512, 2) void lstm_recur(
    const float* __restrict__ XW, const float* __restrict__ Wh,
    float* __restrict__ out) {
  const int j   = threadIdx.x;
  const int b   = blockIdx.x & 31;
  const int dir = blockIdx.x >> 5;

  __shared__ __align__(16) float hs[HN];
  __shared__ float gs[G4];

  float wh[HN];
#pragma unroll
  for (int k = 0; k < HN; k++) wh[k] = Wh[(size_t)k * G4 + j];

  if (j < HN) hs[j] = 0.0f;
  float c = 0.0f, hlast = 0.0f;
  const int gtype = j >> 7;   // 0:i(sig) 1:f(sig) 2:g(tanh) 3:o(sig)
  __syncthreads();

  const float* xwbase = XW + (size_t)b * SEQN * G4 + j;
  float xw_next = xwbase[(size_t)(dir ? (SEQN - 1) : 0) * G4];

  for (int s = 0; s < SEQN; s++) {
    float g = xw_next;
    if (s + 1 < SEQN) {
      const int tn = dir ? (SEQN - 2 - s) : (s + 1);
      xw_next = xwbase[(size_t)tn * G4];
    }

    float a0 = 0.f, a1 = 0.f, a2 = 0.f, a3 = 0.f;
#pragma unroll
    for (int kk = 0; kk < HN / 16; kk++) {
      float4 h0 = *(const float4*)&hs[kk * 16 + 0];
      float4 h1 = *(const float4*)&hs[kk * 16 + 4];
      float4 h2 = *(const float4*)&hs[kk * 16 + 8];
      float4 h3 = *(const float4*)&hs[kk * 16 + 12];
      a0 += h0.x * wh[kk*16+ 0] + h0.y * wh[kk*16+ 1] + h0.z * wh[kk*16+ 2] + h0.w * wh[kk*16+ 3];
      a1 += h1.x * wh[kk*16+ 4] + h1.y * wh[kk*16+ 5] + h1.z * wh[kk*16+ 6] + h1.w * wh[kk*16+ 7];
      a2 += h2.x * wh[kk*16+ 8] + h2.y * wh[kk*16+ 9] + h2.z * wh[kk*16+10] + h2.w * wh[kk*16+11];
      a3 += h3.x * wh[kk*16+12] + h3.y * wh[kk*16+13] + h3.z * wh[kk*16+14] + h3.w * wh[kk*16+15];
    }
    g += (a0 + a1) + (a2 + a3);

    gs[j] = (gtype == 2) ? tanhfast(g) : sigf(g);
    __syncthreads();   // gates visible; all done reading old h

    if (j < HN) {
      const float iv = gs[j];
      const float fv = gs[j + HN];
      const float gv = gs[j + 2 * HN];
      const float ov = gs[j + 3 * HN];
      c = fv * c + iv * gv;
      hlast = ov * tanhfast(c);
      hs[j] = hlast;
      out[((size_t)b * SEQN + s) * (2 * HN) + (size_t)dir * HN + j] = hlast;
    }
    __syncthreads();   // new h visible
  }

  if (j < HN) {
    float* carry = out + OUT_MAIN;
    carry[((size_t)(dir * 2 + 0)) * BATCHN * HN + (size_t)b * HN + j] = hlast; // ht / hinvt
    carry[((size_t)(dir * 2 + 1)) * BATCHN * HN + (size_t)b * HN + j] = c;     // ct / cinvt
  }
}

// ---------------------------------------------------------------------------
// Fallback (workspace too small): compute x@Wi inline each step (slow, correct)
// ---------------------------------------------------------------------------
__global__ __launch_bounds__(512, 2) void lstm_recur_noxw(
    const float* __restrict__ x, const float* __restrict__ Wi,
    const float* __restrict__ Wh, const float* __restrict__ B,
    float* __restrict__ out) {
  const int j   = threadIdx.x;
  const int b   = blockIdx.x & 31;
  const int dir = blockIdx.x >> 5;

  __shared__ __align__(16) float hs[HN];
  __shared__ __align__(16) float xs[INSZ];
  __shared__ float gs[G4];

  float wh[HN];
#pragma unroll
  for (int k = 0; k < HN; k++) wh[k] = Wh[(size_t)k * G4 + j];
  const float bj = B[j];

  if (j < HN) hs[j] = 0.0f;
  float c = 0.0f, hlast = 0.0f;
  const int gtype = j >> 7;
  __syncthreads();

  for (int s = 0; s < SEQN; s++) {
    const int t = dir ? (SEQN - 1 - s) : s;
    if (j < INSZ / 4) {
      ((float4*)xs)[j] = ((const float4*)(x + ((size_t)b * SEQN + t) * INSZ))[j];
    }
    __syncthreads();

    float a0 = bj, a1 = 0.f, a2 = 0.f, a3 = 0.f;
    for (int k = 0; k < INSZ; k += 4) {
      a0 += xs[k + 0] * Wi[(size_t)(k + 0) * G4 + j] + hs[k + 0] * wh[k + 0];
      a1 += xs[k + 1] * Wi[(size_t)(k + 1) * G4 + j] + hs[k + 1] * wh[k + 1];
      a2 += xs[k + 2] * Wi[(size_t)(k + 2) * G4 + j] + hs[k + 2] * wh[k + 2];
      a3 += xs[k + 3] * Wi[(size_t)(k + 3) * G4 + j] + hs[k + 3] * wh[k + 3];
    }
    const float g = (a0 + a1) + (a2 + a3);

    gs[j] = (gtype == 2) ? tanhfast(g) : sigf(g);
    __syncthreads();

    if (j < HN) {
      const float iv = gs[j];
      const float fv = gs[j + HN];
      const float gv = gs[j + 2 * HN];
      const float ov = gs[j + 3 * HN];
      c = fv * c + iv * gv;
      hlast = ov * tanhfast(c);
      hs[j] = hlast;
      out[((size_t)b * SEQN + s) * (2 * HN) + (size_t)dir * HN + j] = hlast;
    }
    __syncthreads();
  }

  if (j < HN) {
    float* carry = out + OUT_MAIN;
    carry[((size_t)(dir * 2 + 0)) * BATCHN * HN + (size_t)b * HN + j] = hlast;
    carry[((size_t)(dir * 2 + 1)) * BATCHN * HN + (size_t)b * HN + j] = c;
  }
}

extern "C" void kernel_launch(void* const* d_in, const int* in_sizes, int n_in,
                              void* d_out, int out_size, void* d_ws, size_t ws_size,
                              hipStream_t stream) {
  const float* x  = (const float*)d_in[0];
  const float* Wi = (const float*)d_in[1];
  const float* Wh = (const float*)d_in[2];
  const float* B  = (const float*)d_in[3];
  float* out = (float*)d_out;

  const size_t xw_bytes = (size_t)BATCHN * SEQN * G4 * sizeof(float);  // 128 MiB
  if (ws_size >= xw_bytes) {
    float* XW = (float*)d_ws;
    precompute_xw<<<dim3(1024), dim3(512), 0, stream>>>(x, Wi, B, XW);
    lstm_recur<<<dim3(64), dim3(512), 0, stream>>>(XW, Wh, out);
  } else {
    lstm_recur_noxw<<<dim3(64), dim3(512), 0, stream>>>(x, Wi, Wh, B, out);
  }
}

// Round 2
// 1778.033 us; speedup vs baseline: 1.4598x; 1.4598x over previous
//
#include <hip/hip_runtime.h>

#define BATCHN 32
#define SEQN   2048
#define INSZ   128
#define HN     128
#define G4     512   // 4*H

#define OUT_MAIN ((size_t)BATCHN * SEQN * 2 * HN)   // 16,777,216 floats

__device__ __forceinline__ float sigf(float x) {
  return 1.0f / (1.0f + __expf(-x));
}
__device__ __forceinline__ float tanhfast(float x) {
  return 2.0f / (1.0f + __expf(-2.0f * x)) - 1.0f;
}

// quad butterfly sum via DPP (VALU pipe, no LDS): lanes 4q..4q+3 all end with
// the sum of their 4 values. quad_perm[1,0,3,2]=0xB1 (xor1), [2,3,0,1]=0x4E (xor2)
__device__ __forceinline__ float qsum(float x) {
  x += __int_as_float(__builtin_amdgcn_update_dpp(
      0, __float_as_int(x), 0xB1, 0xF, 0xF, true));
  x += __int_as_float(__builtin_amdgcn_update_dpp(
      0, __float_as_int(x), 0x4E, 0xF, 0xF, true));
  return x;
}

// barrier WITHOUT vmcnt(0) drain (keeps xw prefetch in flight across steps).
// lgkmcnt(0) makes this wave's ds_write visible before s_barrier.
#define LDS_BARRIER()                                    \
  do {                                                   \
    asm volatile("s_waitcnt lgkmcnt(0)" ::: "memory");   \
    __builtin_amdgcn_s_barrier();                        \
  } while (0)

// ---------------------------------------------------------------------------
// Precompute XW[m][n] = x_flat[m][:] @ Wi[:][n] + B[n],  m=b*SEQN+t (65536), n=0..511
// Register-tiled GEMM: 64x64 tile per block, K=128 fully resident in LDS.
// 256 threads, 4x4 outputs each. grid = (1024, 8).
// ---------------------------------------------------------------------------
__global__ __launch_bounds__(256, 2) void precompute_xw(
    const float* __restrict__ x, const float* __restrict__ Wi,
    const float* __restrict__ B, float* __restrict__ XW) {
  __shared__ float As[INSZ][64];   // As[k][m] = x[m0+m][k]   32 KiB
  __shared__ float Bs[INSZ][64];   // Bs[k][n] = Wi[k][n0+n]  32 KiB

  const int tid = threadIdx.x;
  const int m0 = blockIdx.x * 64;
  const int n0 = blockIdx.y * 64;

  // x tile: lane -> row (consecutive rows => conflict-free LDS writes)
  {
    const int row = tid & 63;
    const int k4b = tid >> 6;    // 0..3
    const float4* xs4 = (const float4*)(x + (size_t)(m0 + row) * INSZ);
#pragma unroll
    for (int it = 0; it < 8; it++) {
      const int k4 = k4b + (it << 2);       // 0..31
      float4 v = xs4[k4];
      As[k4 * 4 + 0][row] = v.x;
      As[k4 * 4 + 1][row] = v.y;
      As[k4 * 4 + 2][row] = v.z;
      As[k4 * 4 + 3][row] = v.w;
    }
  }
  // Wi tile: coalesced rows of 64
  {
    const int n4 = tid & 15;
    const int kb = tid >> 4;     // 0..15
#pragma unroll
    for (int it = 0; it < 8; it++) {
      const int k = kb + (it << 4);         // 0..127
      float4 v = *(const float4*)(Wi + (size_t)k * G4 + n0 + n4 * 4);
      *(float4*)&Bs[k][n4 * 4] = v;
    }
  }
  __syncthreads();

  const int tx = tid & 15;       // n-subtile
  const int ty = tid >> 4;       // m-subtile
  float4 acc0 = {0, 0, 0, 0}, acc1 = {0, 0, 0, 0};
  float4 acc2 = {0, 0, 0, 0}, acc3 = {0, 0, 0, 0};

#pragma unroll 8
  for (int k = 0; k < INSZ; k++) {
    const float4 a = *(const float4*)&As[k][ty * 4];
    const float4 bv = *(const float4*)&Bs[k][tx * 4];
    acc0.x += a.x * bv.x; acc0.y += a.x * bv.y; acc0.z += a.x * bv.z; acc0.w += a.x * bv.w;
    acc1.x += a.y * bv.x; acc1.y += a.y * bv.y; acc1.z += a.y * bv.z; acc1.w += a.y * bv.w;
    acc2.x += a.z * bv.x; acc2.y += a.z * bv.y; acc2.z += a.z * bv.z; acc2.w += a.z * bv.w;
    acc3.x += a.w * bv.x; acc3.y += a.w * bv.y; acc3.z += a.w * bv.z; acc3.w += a.w * bv.w;
  }

  const float4 bb = *(const float4*)(B + n0 + tx * 4);
  float* dst = XW + (size_t)(m0 + ty * 4) * G4 + n0 + tx * 4;
  float4 o;
  o.x = acc0.x + bb.x; o.y = acc0.y + bb.y; o.z = acc0.z + bb.z; o.w = acc0.w + bb.w;
  *(float4*)(dst + 0 * G4) = o;
  o.x = acc1.x + bb.x; o.y = acc1.y + bb.y; o.z = acc1.z + bb.z; o.w = acc1.w + bb.w;
  *(float4*)(dst + 1 * G4) = o;
  o.x = acc2.x + bb.x; o.y = acc2.y + bb.y; o.z = acc2.z + bb.z; o.w = acc2.w + bb.w;
  *(float4*)(dst + 2 * G4) = o;
  o.x = acc3.x + bb.x; o.y = acc3.y + bb.y; o.z = acc3.z + bb.z; o.w = acc3.w + bb.w;
  *(float4*)(dst + 3 * G4) = o;
}

// ---------------------------------------------------------------------------
// Recurrence: 64 blocks = (batch 32) x (dir 2). 512 threads = 128 h-elements
// x 4 k-quads. Thread (j, kq) holds Wh columns {j, j+128, j+256, j+384}
// restricted to k in [kq*32, kq*32+32) => 128 VGPRs. Per step: read own
// 32-float h slice (8x ds_read_b128, bank-rotated), 128 fmac, DPP quad-reduce,
// activations, h/c update — all 4 gates local, no exchange, 1 barrier/step.
// ---------------------------------------------------------------------------
__global__ __launch_bounds__(512, 2) void lstm_recur(
    const float* __restrict__ XW, const float* __restrict__ Wh,
    float* __restrict__ out) {
  const int tid = threadIdx.x;
  const int l   = tid & 63;
  const int w   = tid >> 6;          // wave 0..7
  const int kq  = l & 3;             // k-quad
  const int jl  = l >> 2;            // 0..15
  const int j   = w * 16 + jl;       // h element 0..127
  const int b   = blockIdx.x & 31;
  const int dir = blockIdx.x >> 5;

  __shared__ float hs[2][HN];

  // Wh fragment in rotated k-order: reg (i,q) <-> k = kq*32 + ((i+2kq)&7)*4 + q
  // (rotation makes the 4 concurrent per-quad LDS read addrs hit distinct banks)
  float wh0[32], wh1[32], wh2[32], wh3[32];
#pragma unroll
  for (int i = 0; i < 8; i++) {
    const int ch = (i + 2 * kq) & 7;
    const int kbase = kq * 32 + ch * 4;
#pragma unroll
    for (int q = 0; q < 4; q++) {
      const size_t r = (size_t)(kbase + q) * G4;
      wh0[i * 4 + q] = Wh[r + 0 * HN + j];
      wh1[i * 4 + q] = Wh[r + 1 * HN + j];
      wh2[i * 4 + q] = Wh[r + 2 * HN + j];
      wh3[i * 4 + q] = Wh[r + 3 * HN + j];
    }
  }
  // xw routing masks: thread kq contributes XW gate column kq (added pre-reduce)
  const float m0 = (kq == 0) ? 1.f : 0.f;
  const float m1 = (kq == 1) ? 1.f : 0.f;
  const float m2 = (kq == 2) ? 1.f : 0.f;
  const float m3 = (kq == 3) ? 1.f : 0.f;

  if (tid < HN) hs[0][tid] = 0.f;
  float c = 0.f, h = 0.f;
  __syncthreads();

  const float* xwp = XW + (size_t)b * SEQN * G4 + kq * HN + j;
  float xw_cur = xwp[(size_t)(dir ? SEQN - 1 : 0) * G4];
  float xw_nxt = 0.f;

#pragma unroll 2
  for (int s = 0; s < SEQN; s++) {
    // prefetch next step's xw (stays in flight across the barrier)
    if (s < SEQN - 1) {
      const int tn = dir ? (SEQN - 2 - s) : (s + 1);
      xw_nxt = xwp[(size_t)tn * G4];
    }
    const int par = s & 1;
    const float* hrow = hs[par];

    float hbuf[32];
#pragma unroll
    for (int i = 0; i < 8; i++) {
      const int ch = (i + 2 * kq) & 7;
      *(float4*)&hbuf[i * 4] = *(const float4*)&hrow[kq * 32 + ch * 4];
    }

    float a0 = 0.f, a1 = 0.f, a2 = 0.f, a3 = 0.f;
#pragma unroll
    for (int k = 0; k < 32; k++) {
      a0 += hbuf[k] * wh0[k];
      a1 += hbuf[k] * wh1[k];
      a2 += hbuf[k] * wh2[k];
      a3 += hbuf[k] * wh3[k];
    }
    a0 += m0 * xw_cur;
    a1 += m1 * xw_cur;
    a2 += m2 * xw_cur;
    a3 += m3 * xw_cur;

    a0 = qsum(a0); a1 = qsum(a1); a2 = qsum(a2); a3 = qsum(a3);

    const float iv = sigf(a0);
    const float fv = sigf(a1);
    const float gv = tanhfast(a2);
    const float ov = sigf(a3);
    c = fv * c + iv * gv;
    h = ov * tanhfast(c);

    if (kq == 0) {
      hs[par ^ 1][j] = h;
      out[((size_t)b * SEQN + s) * (2 * HN) + (size_t)dir * HN + j] = h;
    }
    LDS_BARRIER();
    xw_cur = xw_nxt;
  }

  if (kq == 0) {
    float* carry = out + OUT_MAIN;
    carry[(size_t)(dir * 2 + 0) * BATCHN * HN + (size_t)b * HN + j] = h;
    carry[(size_t)(dir * 2 + 1) * BATCHN * HN + (size_t)b * HN + j] = c;
  }
}

// ---------------------------------------------------------------------------
// Fallback (workspace too small): compute x@Wi inline each step (slow, correct)
// ---------------------------------------------------------------------------
__global__ __launch_bounds__(512, 2) void lstm_recur_noxw(
    const float* __restrict__ x, const float* __restrict__ Wi,
    const float* __restrict__ Wh, const float* __restrict__ B,
    float* __restrict__ out) {
  const int j   = threadIdx.x;
  const int b   = blockIdx.x & 31;
  const int dir = blockIdx.x >> 5;

  __shared__ __align__(16) float hs[HN];
  __shared__ __align__(16) float xs[INSZ];
  __shared__ float gs[G4];

  float wh[HN];
#pragma unroll
  for (int k = 0; k < HN; k++) wh[k] = Wh[(size_t)k * G4 + j];
  const float bj = B[j];

  if (j < HN) hs[j] = 0.0f;
  float c = 0.0f, hlast = 0.0f;
  const int gtype = j >> 7;
  __syncthreads();

  for (int s = 0; s < SEQN; s++) {
    const int t = dir ? (SEQN - 1 - s) : s;
    if (j < INSZ / 4) {
      ((float4*)xs)[j] = ((const float4*)(x + ((size_t)b * SEQN + t) * INSZ))[j];
    }
    __syncthreads();

    float a0 = bj, a1 = 0.f, a2 = 0.f, a3 = 0.f;
    for (int k = 0; k < INSZ; k += 4) {
      a0 += xs[k + 0] * Wi[(size_t)(k + 0) * G4 + j] + hs[k + 0] * wh[k + 0];
      a1 += xs[k + 1] * Wi[(size_t)(k + 1) * G4 + j] + hs[k + 1] * wh[k + 1];
      a2 += xs[k + 2] * Wi[(size_t)(k + 2) * G4 + j] + hs[k + 2] * wh[k + 2];
      a3 += xs[k + 3] * Wi[(size_t)(k + 3) * G4 + j] + hs[k + 3] * wh[k + 3];
    }
    const float g = (a0 + a1) + (a2 + a3);

    gs[j] = (gtype == 2) ? tanhfast(g) : sigf(g);
    __syncthreads();

    if (j < HN) {
      const float iv = gs[j];
      const float fv = gs[j + HN];
      const float gv = gs[j + 2 * HN];
      const float ov = gs[j + 3 * HN];
      c = fv * c + iv * gv;
      hlast = ov * tanhfast(c);
      hs[j] = hlast;
      out[((size_t)b * SEQN + s) * (2 * HN) + (size_t)dir * HN + j] = hlast;
    }
    __syncthreads();
  }

  if (j < HN) {
    float* carry = out + OUT_MAIN;
    carry[((size_t)(dir * 2 + 0)) * BATCHN * HN + (size_t)b * HN + j] = hlast;
    carry[((size_t)(dir * 2 + 1)) * BATCHN * HN + (size_t)b * HN + j] = c;
  }
}

extern "C" void kernel_launch(void* const* d_in, const int* in_sizes, int n_in,
                              void* d_out, int out_size, void* d_ws, size_t ws_size,
                              hipStream_t stream) {
  const float* x  = (const float*)d_in[0];
  const float* Wi = (const float*)d_in[1];
  const float* Wh = (const float*)d_in[2];
  const float* B  = (const float*)d_in[3];
  float* out = (float*)d_out;

  const size_t xw_bytes = (size_t)BATCHN * SEQN * G4 * sizeof(float);  // 128 MiB
  if (ws_size >= xw_bytes) {
    float* XW = (float*)d_ws;
    precompute_xw<<<dim3(1024, 8), dim3(256), 0, stream>>>(x, Wi, B, XW);
    lstm_recur<<<dim3(64), dim3(512), 0, stream>>>(XW, Wh, out);
  } else {
    lstm_recur_noxw<<<dim3(64), dim3(512), 0, stream>>>(x, Wi, Wh, B, out);
  }
}

// Round 4
// 1207.866 us; speedup vs baseline: 2.1489x; 1.4720x over previous
//
#include <hip/hip_runtime.h>

#define BATCHN 32
#define SEQN   2048
#define INSZ   128
#define HN     128
#define G4     512   // 4*H

#define OUT_MAIN ((size_t)BATCHN * SEQN * 2 * HN)   // 16,777,216 floats

__device__ __forceinline__ float fast_rcp(float x) {
  return __builtin_amdgcn_rcpf(x);   // v_rcp_f32, ~1 ulp
}

// quad butterfly sum via DPP: all 4 quad lanes end with the quad's sum
__device__ __forceinline__ float qsum(float x) {
  x += __int_as_float(__builtin_amdgcn_update_dpp(
      0, __float_as_int(x), 0xB1, 0xF, 0xF, true));   // quad_perm [1,0,3,2]
  x += __int_as_float(__builtin_amdgcn_update_dpp(
      0, __float_as_int(x), 0x4E, 0xF, 0xF, true));   // quad_perm [2,3,0,1]
  return x;
}

// broadcast quad lane Q to all 4 lanes of the quad (IMM = Q*0b01010101)
template <int IMM>
__device__ __forceinline__ float qperm(float x) {
  return __int_as_float(__builtin_amdgcn_update_dpp(
      0, __float_as_int(x), IMM, 0xF, 0xF, true));
}

// ---------------------------------------------------------------------------
// Precompute XW[m][n] = x_flat[m][:] @ Wi[:][n] + B[n]
// Register-tiled GEMM: 64x64 tile, K=128 resident in LDS. (~80 µs)
// ---------------------------------------------------------------------------
__global__ __launch_bounds__(256, 2) void precompute_xw(
    const float* __restrict__ x, const float* __restrict__ Wi,
    const float* __restrict__ B, float* __restrict__ XW) {
  __shared__ float As[INSZ][64];
  __shared__ float Bs[INSZ][64];

  const int tid = threadIdx.x;
  const int m0 = blockIdx.x * 64;
  const int n0 = blockIdx.y * 64;

  {
    const int row = tid & 63;
    const int k4b = tid >> 6;
    const float4* xs4 = (const float4*)(x + (size_t)(m0 + row) * INSZ);
#pragma unroll
    for (int it = 0; it < 8; it++) {
      const int k4 = k4b + (it << 2);
      float4 v = xs4[k4];
      As[k4 * 4 + 0][row] = v.x;
      As[k4 * 4 + 1][row] = v.y;
      As[k4 * 4 + 2][row] = v.z;
      As[k4 * 4 + 3][row] = v.w;
    }
  }
  {
    const int n4 = tid & 15;
    const int kb = tid >> 4;
#pragma unroll
    for (int it = 0; it < 8; it++) {
      const int k = kb + (it << 4);
      float4 v = *(const float4*)(Wi + (size_t)k * G4 + n0 + n4 * 4);
      *(float4*)&Bs[k][n4 * 4] = v;
    }
  }
  __syncthreads();

  const int tx = tid & 15;
  const int ty = tid >> 4;
  float4 acc0 = {0, 0, 0, 0}, acc1 = {0, 0, 0, 0};
  float4 acc2 = {0, 0, 0, 0}, acc3 = {0, 0, 0, 0};

#pragma unroll 8
  for (int k = 0; k < INSZ; k++) {
    const float4 a = *(const float4*)&As[k][ty * 4];
    const float4 bv = *(const float4*)&Bs[k][tx * 4];
    acc0.x += a.x * bv.x; acc0.y += a.x * bv.y; acc0.z += a.x * bv.z; acc0.w += a.x * bv.w;
    acc1.x += a.y * bv.x; acc1.y += a.y * bv.y; acc1.z += a.y * bv.z; acc1.w += a.y * bv.w;
    acc2.x += a.z * bv.x; acc2.y += a.z * bv.y; acc2.z += a.z * bv.z; acc2.w += a.z * bv.w;
    acc3.x += a.w * bv.x; acc3.y += a.w * bv.y; acc3.z += a.w * bv.z; acc3.w += a.w * bv.w;
  }

  const float4 bb = *(const float4*)(B + n0 + tx * 4);
  float* dst = XW + (size_t)(m0 + ty * 4) * G4 + n0 + tx * 4;
  float4 o;
  o.x = acc0.x + bb.x; o.y = acc0.y + bb.y; o.z = acc0.z + bb.z; o.w = acc0.w + bb.w;
  *(float4*)(dst + 0 * G4) = o;
  o.x = acc1.x + bb.x; o.y = acc1.y + bb.y; o.z = acc1.z + bb.z; o.w = acc1.w + bb.w;
  *(float4*)(dst + 1 * G4) = o;
  o.x = acc2.x + bb.x; o.y = acc2.y + bb.y; o.z = acc2.z + bb.z; o.w = acc2.w + bb.w;
  *(float4*)(dst + 2 * G4) = o;
  o.x = acc3.x + bb.x; o.y = acc3.y + bb.y; o.z = acc3.z + bb.z; o.w = acc3.w + bb.w;
  *(float4*)(dst + 3 * G4) = o;
}

// ---------------------------------------------------------------------------
// Recurrence: 64 blocks = chain (b, dir). 512 threads = 128 j x 4 k-quads.
// Thread (j,kq): Wh cols {j,j+128,j+256,j+384} restricted to k in
// [kq*32,kq*32+32) = 128 VGPRs. Per step: 8 bank-rotated ds_read_b128
// (streamed), 128 fmac, DPP quad-reduce, per-lane single-gate activation
// (2 transcendentals), quad_perm gather of i/f/g/o, c/h update.
// xw prefetched 2 steps ahead. 1 barrier/step, manual 2x unroll.
// ---------------------------------------------------------------------------
__global__ __launch_bounds__(512, 2) void lstm_recur(
    const float* __restrict__ XW, const float* __restrict__ Wh,
    float* __restrict__ out) {
  const int tid = threadIdx.x;
  const int l   = tid & 63;
  const int w   = tid >> 6;
  const int kq  = l & 3;
  const int jl  = l >> 2;
  const int j   = w * 16 + jl;
  const int b   = blockIdx.x & 31;
  const int dir = blockIdx.x >> 5;

  __shared__ float hs[2][HN];

  // Wh fragment, bank-rotated k order: reg (i,q) <-> k = kq*32 + ((i+2kq)&7)*4 + q
  float wh0[32], wh1[32], wh2[32], wh3[32];
#pragma unroll
  for (int i = 0; i < 8; i++) {
    const int ch = (i + 2 * kq) & 7;
    const int kbase = kq * 32 + ch * 4;
#pragma unroll
    for (int q = 0; q < 4; q++) {
      const size_t r = (size_t)(kbase + q) * G4;
      wh0[i * 4 + q] = Wh[r + 0 * HN + j];
      wh1[i * 4 + q] = Wh[r + 1 * HN + j];
      wh2[i * 4 + q] = Wh[r + 2 * HN + j];
      wh3[i * 4 + q] = Wh[r + 3 * HN + j];
    }
  }

  // hoisted per-lane activation constants: lane kq applies only gate kq.
  // gate 2 (g) is tanh = 2*sig(2x)-1; others sigmoid.
  const bool k0 = (kq == 0), k1 = (kq == 1), k2 = (kq == 2);
  const float xsc = k2 ? -2.0f : -1.0f;   // exp argument scale
  const float asc = k2 ? 2.0f : 1.0f;     // act = asc*r + abi
  const float abi = k2 ? -1.0f : 0.0f;

  if (tid < HN) hs[0][tid] = 0.f;
  float c = 0.f, h = 0.f;
  __syncthreads();

  // own (gate=kq, j) xw column; time index ts(s) = dir ? SEQN-1-s : s
  const float* xwp = XW + (size_t)b * SEQN * G4 + (size_t)kq * HN + j;
  float xwA = xwp[(size_t)(dir ? SEQN - 1 : 0) * G4];
  float xwB = xwp[(size_t)(dir ? SEQN - 2 : 1) * G4];

#define LSTM_STEP(S, PAR, XWREG)                                               \
  {                                                                            \
    const int tpf = ((S) + 2 < SEQN) ? (S) + 2 : SEQN - 1;                     \
    const float xw_pf = xwp[(size_t)(dir ? (SEQN - 1 - tpf) : tpf) * G4];      \
    float a0 = 0.f, a1 = 0.f, a2 = 0.f, a3 = 0.f;                              \
    _Pragma("unroll")                                                          \
    for (int i = 0; i < 8; i++) {                                              \
      const int ch = (i + 2 * kq) & 7;                                         \
      const float4 hv = *(const float4*)&hs[PAR][kq * 32 + ch * 4];            \
      a0 += hv.x * wh0[i * 4 + 0]; a1 += hv.x * wh1[i * 4 + 0];                \
      a2 += hv.x * wh2[i * 4 + 0]; a3 += hv.x * wh3[i * 4 + 0];                \
      a0 += hv.y * wh0[i * 4 + 1]; a1 += hv.y * wh1[i * 4 + 1];                \
      a2 += hv.y * wh2[i * 4 + 1]; a3 += hv.y * wh3[i * 4 + 1];                \
      a0 += hv.z * wh0[i * 4 + 2]; a1 += hv.z * wh1[i * 4 + 2];                \
      a2 += hv.z * wh2[i * 4 + 2]; a3 += hv.z * wh3[i * 4 + 2];                \
      a0 += hv.w * wh0[i * 4 + 3]; a1 += hv.w * wh1[i * 4 + 3];                \
      a2 += hv.w * wh2[i * 4 + 3]; a3 += hv.w * wh3[i * 4 + 3];                \
    }                                                                          \
    a0 = qsum(a0); a1 = qsum(a1); a2 = qsum(a2); a3 = qsum(a3);                \
    float sel = k0 ? a0 : (k1 ? a1 : (k2 ? a2 : a3));                          \
    sel += XWREG;                                                              \
    const float e   = __expf(sel * xsc);                                       \
    const float r   = fast_rcp(1.0f + e);                                      \
    const float act = r * asc + abi;                                           \
    const float iv = qperm<0x00>(act);                                         \
    const float fv = qperm<0x55>(act);                                         \
    const float gv = qperm<0xAA>(act);                                         \
    const float ov = qperm<0xFF>(act);                                         \
    c = fv * c + iv * gv;                                                      \
    const float e2 = __expf(-2.0f * c);                                        \
    const float th = 2.0f * fast_rcp(1.0f + e2) - 1.0f;                        \
    h = ov * th;                                                               \
    if (kq == 0) {                                                             \
      hs[(PAR) ^ 1][j] = h;                                                    \
      out[((size_t)b * SEQN + (S)) * (2 * HN) + (size_t)dir * HN + j] = h;     \
    }                                                                          \
    asm volatile("s_waitcnt lgkmcnt(0)" ::: "memory");                         \
    __builtin_amdgcn_s_barrier();                                              \
    XWREG = xw_pf;                                                             \
  }

  for (int s = 0; s < SEQN; s += 2) {
    LSTM_STEP(s, 0, xwA);
    LSTM_STEP(s + 1, 1, xwB);
  }
#undef LSTM_STEP

  if (kq == 0) {
    float* carry = out + OUT_MAIN;
    carry[(size_t)(dir * 2 + 0) * BATCHN * HN + (size_t)b * HN + j] = h;
    carry[(size_t)(dir * 2 + 1) * BATCHN * HN + (size_t)b * HN + j] = c;
  }
}

// ---------------------------------------------------------------------------
// Fallback (workspace too small): compute x@Wi inline each step (slow, correct)
// ---------------------------------------------------------------------------
__global__ __launch_bounds__(512, 2) void lstm_recur_noxw(
    const float* __restrict__ x, const float* __restrict__ Wi,
    const float* __restrict__ Wh, const float* __restrict__ B,
    float* __restrict__ out) {
  const int j   = threadIdx.x;
  const int b   = blockIdx.x & 31;
  const int dir = blockIdx.x >> 5;

  __shared__ __align__(16) float hs[HN];
  __shared__ __align__(16) float xs[INSZ];
  __shared__ float gs[G4];

  float wh[HN];
#pragma unroll
  for (int k = 0; k < HN; k++) wh[k] = Wh[(size_t)k * G4 + j];
  const float bj = B[j];

  if (j < HN) hs[j] = 0.0f;
  float c = 0.0f, hlast = 0.0f;
  const int gtype = j >> 7;
  __syncthreads();

  for (int s = 0; s < SEQN; s++) {
    const int t = dir ? (SEQN - 1 - s) : s;
    if (j < INSZ / 4) {
      ((float4*)xs)[j] = ((const float4*)(x + ((size_t)b * SEQN + t) * INSZ))[j];
    }
    __syncthreads();

    float a0 = bj, a1 = 0.f, a2 = 0.f, a3 = 0.f;
    for (int k = 0; k < INSZ; k += 4) {
      a0 += xs[k + 0] * Wi[(size_t)(k + 0) * G4 + j] + hs[k + 0] * wh[k + 0];
      a1 += xs[k + 1] * Wi[(size_t)(k + 1) * G4 + j] + hs[k + 1] * wh[k + 1];
      a2 += xs[k + 2] * Wi[(size_t)(k + 2) * G4 + j] + hs[k + 2] * wh[k + 2];
      a3 += xs[k + 3] * Wi[(size_t)(k + 3) * G4 + j] + hs[k + 3] * wh[k + 3];
    }
    const float g = (a0 + a1) + (a2 + a3);

    float act;
    if (gtype == 2) act = 2.f * fast_rcp(1.f + __expf(-2.f * g)) - 1.f;
    else            act = fast_rcp(1.f + __expf(-g));
    gs[j] = act;
    __syncthreads();

    if (j < HN) {
      const float iv = gs[j];
      const float fv = gs[j + HN];
      const float gv = gs[j + 2 * HN];
      const float ov = gs[j + 3 * HN];
      c = fv * c + iv * gv;
      hlast = ov * (2.f * fast_rcp(1.f + __expf(-2.f * c)) - 1.f);
      hs[j] = hlast;
      out[((size_t)b * SEQN + s) * (2 * HN) + (size_t)dir * HN + j] = hlast;
    }
    __syncthreads();
  }

  if (j < HN) {
    float* carry = out + OUT_MAIN;
    carry[((size_t)(dir * 2 + 0)) * BATCHN * HN + (size_t)b * HN + j] = hlast;
    carry[((size_t)(dir * 2 + 1)) * BATCHN * HN + (size_t)b * HN + j] = c;
  }
}

extern "C" void kernel_launch(void* const* d_in, const int* in_sizes, int n_in,
                              void* d_out, int out_size, void* d_ws, size_t ws_size,
                              hipStream_t stream) {
  const float* x  = (const float*)d_in[0];
  const float* Wi = (const float*)d_in[1];
  const float* Wh = (const float*)d_in[2];
  const float* B  = (const float*)d_in[3];
  float* out = (float*)d_out;

  const size_t xw_bytes = (size_t)BATCHN * SEQN * G4 * sizeof(float);  // 128 MiB
  if (ws_size >= xw_bytes) {
    float* XW = (float*)d_ws;
    precompute_xw<<<dim3(1024, 8), dim3(256), 0, stream>>>(x, Wi, B, XW);
    lstm_recur<<<dim3(64), dim3(512), 0, stream>>>(XW, Wh, out);
  } else {
    lstm_recur_noxw<<<dim3(64), dim3(512), 0, stream>>>(x, Wi, Wh, B, out);
  }
}